// Round 6
// baseline (153.874 us; speedup 1.0000x reference)
//
#include <hip/hip_runtime.h>
#include <hip/hip_bf16.h>

typedef __bf16 bf16_t;
typedef __bf16 bf16x2 __attribute__((ext_vector_type(2)));
typedef __bf16 bf16x8 __attribute__((ext_vector_type(8)));
typedef float  f32x4  __attribute__((ext_vector_type(4)));

#define MFMA16(A,B,C) __builtin_amdgcn_mfma_f32_16x16x32_bf16((A),(B),(C),0,0,0)

constexpr int Bn = 2, Cc = 128, Hh = 64, Wd = 64;
constexpr int N  = Hh * Wd;      // 4096 tokens per batch
constexpr int T  = Bn * N;       // 8192 tokens total
constexpr int D  = 2 * Cc;       // 256 = [real | imag] channels
constexpr int NSP = 4;           // key splits
constexpr float EPS = 1e-5f;
constexpr float SCL = 0.08838834764831845f * 1.4426950408889634f; // C^-0.5 * log2(e), folded into Q

// 64-row x 256-ch bf16 A-tile (32 KB), fragment-ordered (16x16x32 MFMA):
//   frag = (ch>>5)*4 + (row>>4); lane = ((ch>>3)&3)*16 + (row&15); elem = ch&7
__device__ __forceinline__ int tfrag(int row, int ch) {
    return (((ch >> 5) * 4 + (row >> 4)) << 10) +
           ((((ch >> 3) & 3) * 16 + (row & 15)) << 4) + (ch & 7) * 2;
}
// K tile: 32 keys x 256 ch (16 KB), B-frags (16 keys x 32 ch)
__device__ __forceinline__ int kfrag32(int key, int ch) {
    return (((ch >> 5) * 2 + (key >> 4)) << 10) +
           ((((ch >> 3) & 3) * 16 + (key & 15)) << 4) + (ch & 7) * 2;
}
// V tile: 256 ch x 32 keys (16 KB), B-frags (16 ch x 32 keys)
__device__ __forceinline__ int vfrag32(int ch, int key) {
    return ((ch >> 4) << 10) +
           ((((key >> 3) & 3) * 16 + (ch & 15)) << 4) + (key & 7) * 2;
}

__device__ __forceinline__ void gl16(const void* g, void* l) {
    __builtin_amdgcn_global_load_lds(
        (const __attribute__((address_space(1))) void*)g,
        (__attribute__((address_space(3))) void*)l, 16, 0, 0);
}

// ---- kernel 1: fused BN partial stats (blocks 0..511) + weight prep (512..1279)
__global__ void k_pre(const float* __restrict__ x, float4* __restrict__ part,
                      const float* __restrict__ wq, const float* __restrict__ wk,
                      const float* __restrict__ wv, const float* __restrict__ bq,
                      const float* __restrict__ bk, const float* __restrict__ bv,
                      char* __restrict__ Wg, float* __restrict__ bt) {
    int tid = threadIdx.x;
    if (blockIdx.x < 512) {
        int bid = blockIdx.x;            // q*128 + c
        int q = bid >> 7, c = bid & 127;
        float sr = 0.f, si = 0.f, qr = 0.f, qi = 0.f;
        for (int b = 0; b < Bn; ++b) {
            const float2* p = (const float2*)x + (size_t)(b * Cc + c) * N + q * 1024;
            for (int i = tid; i < 1024; i += 256) {
                float2 v = p[i];
                sr += v.x; si += v.y; qr += v.x * v.x; qi += v.y * v.y;
            }
        }
        #pragma unroll
        for (int d = 32; d >= 1; d >>= 1) {
            sr += __shfl_xor(sr, d); si += __shfl_xor(si, d);
            qr += __shfl_xor(qr, d); qi += __shfl_xor(qi, d);
        }
        __shared__ float red[4][4];
        int w = tid >> 6;
        if ((tid & 63) == 0) { red[w][0] = sr; red[w][1] = si; red[w][2] = qr; red[w][3] = qi; }
        __syncthreads();
        if (tid == 0) {
            part[c * 4 + q] = make_float4(red[0][0] + red[1][0] + red[2][0] + red[3][0],
                                          red[0][1] + red[1][1] + red[2][1] + red[3][1],
                                          red[0][2] + red[1][2] + red[2][2] + red[3][2],
                                          red[0][3] + red[1][3] + red[2][3] + red[3][3]);
        }
    } else {
        int o = blockIdx.x - 512;        // 768 = [Qr Qi Kr Ki Vr Vi] x128
        int k = tid;
        int proj = o >> 8, oc = o & 255;
        const float* wsrc = proj == 0 ? wq : (proj == 1 ? wk : wv);
        const float* bsrc = proj == 0 ? bq : (proj == 1 ? bk : bv);
        int co = oc >> 7, oo = oc & 127;
        int c = k & 127, kc = k >> 7;
        float val;
        if (co == 0) val = (kc == 0) ? wsrc[(oo * 128 + c) * 2 + 0] : -wsrc[(oo * 128 + c) * 2 + 1];
        else         val = (kc == 0) ? wsrc[(oo * 128 + c) * 2 + 1] :  wsrc[(oo * 128 + c) * 2 + 0];
        float fs = (proj == 0) ? SCL : 1.0f;   // fold softmax scale into Q
        int tile = o >> 6, row = o & 63;
        *(bf16_t*)(Wg + (size_t)tile * 32768 + tfrag(row, k)) = (bf16_t)(val * fs);
        if (k == 0) bt[o] = bsrc[oo * 2 + co] * fs;
    }
}

// ---- kernel 2: fused normalize + QKV GEMM. Each block re-normalizes its own
// X tile (x fp32 is L3-resident; ssl finalize is trivial). W via gl16.
__global__ __launch_bounds__(256) void k_qkv(const float* __restrict__ x,
        const float4* __restrict__ part, const float* __restrict__ bn_w,
        const float* __restrict__ bn_b, const char* __restrict__ Wg,
        const float* __restrict__ bt,
        char* __restrict__ Qg, char* __restrict__ Kg, char* __restrict__ Vg) {
    __shared__ __align__(16) char Xsh[32768];
    __shared__ __align__(16) char Wsh[32768];
    __shared__ float4 ssl[128];
    int mx = blockIdx.x, ny = blockIdx.y;   // 128 x 12
    int tid = threadIdx.x;
    int w = tid >> 6, lane = tid & 63, n15 = lane & 15, quad = lane >> 4;
    const char* wsp = Wg + (size_t)ny * 32768;
    #pragma unroll
    for (int i = 0; i < 8; ++i) {
        int off = (w * 8 + i) * 1024 + lane * 16;
        gl16(wsp + off, Wsh + off);
    }
    if (tid < 128) {
        float4 p0 = part[tid * 4 + 0], p1 = part[tid * 4 + 1];
        float4 p2 = part[tid * 4 + 2], p3 = part[tid * 4 + 3];
        float sr = p0.x + p1.x + p2.x + p3.x, si = p0.y + p1.y + p2.y + p3.y;
        float qr = p0.z + p1.z + p2.z + p3.z, qi = p0.w + p1.w + p2.w + p3.w;
        const float inv = 1.0f / (float)(Bn * N);
        float mr = sr * inv, mi = si * inv;
        float vr = qr * inv - mr * mr, vi = qi * inv - mi * mi;
        float scr = bn_w[tid * 2 + 0] * rsqrtf(vr + EPS);
        float sci = bn_w[tid * 2 + 1] * rsqrtf(vi + EPS);
        ssl[tid] = make_float4(scr, bn_b[tid * 2 + 0] - mr * scr,
                               sci, bn_b[tid * 2 + 1] - mi * sci);
    }
    __syncthreads();   // ssl visible (W DMA drains here too; issued early)
    int b = mx >> 6, hw0 = (mx & 63) * 64;
    const float2* xin = (const float2*)x;
    #pragma unroll
    for (int it = 0; it < 16; ++it) {
        int idx = it * 256 + tid;
        int cp = idx >> 6, hw = idx & 63;   // channel pair cp -> ch 2cp, 2cp+1
        size_t gi = (size_t)(b * Cc + cp * 2) * N + hw0 + hw;
        float2 v0 = xin[gi], v1 = xin[gi + N];
        float4 s0 = ssl[cp * 2], s1 = ssl[cp * 2 + 1];
        bf16x2 pr, pi;
        pr[0] = (bf16_t)(v0.x * s0.x + s0.y); pr[1] = (bf16_t)(v1.x * s1.x + s1.y);
        pi[0] = (bf16_t)(v0.y * s0.z + s0.w); pi[1] = (bf16_t)(v1.y * s1.z + s1.w);
        *(bf16x2*)(Xsh + tfrag(hw, cp * 2))       = pr;
        *(bf16x2*)(Xsh + tfrag(hw, cp * 2 + 128)) = pi;
    }
    __syncthreads();
    f32x4 acc[4] = {};
    #pragma unroll
    for (int ks = 0; ks < 8; ++ks) {
        bf16x8 a = *(const bf16x8*)(Xsh + (ks * 4 + w) * 1024 + lane * 16);
        #pragma unroll
        for (int t = 0; t < 4; ++t) {
            bf16x8 bw = *(const bf16x8*)(Wsh + (ks * 4 + t) * 1024 + lane * 16);
            acc[t] = MFMA16(a, bw, acc[t]);
        }
    }
    int proj = ny >> 2;            // 0=Q 1=K 2=V
    int jb = (ny & 3) * 64;
    #pragma unroll
    for (int t = 0; t < 4; ++t) {
        int j = jb + t * 16 + n15;
        float bias = bt[ny * 64 + t * 16 + n15];
        #pragma unroll
        for (int r = 0; r < 4; ++r) {
            int tk = mx * 64 + w * 16 + quad * 4 + r;
            float v = acc[t][r] + bias;
            int bb = tk >> 12, n = tk & (N - 1);
            if (proj == 0) {
                *(bf16_t*)(Qg + (size_t)(tk >> 6) * 32768 + tfrag(tk & 63, j)) = (bf16_t)v;
            } else {
                size_t tb = (size_t)(bb * 128 + (n >> 5)) * 16384;
                if (proj == 1) *(bf16_t*)(Kg + tb + kfrag32(n & 31, j)) = (bf16_t)v;
                else           *(bf16_t*)(Vg + tb + vfrag32(j, n & 31)) = (bf16_t)v;
            }
        }
    }
}

// ---- kernel 3: flash attention, BC=32, double-buffered staging.
// Wave (r,h): QK rows r*32 x keys h*16; PV rows r*32 x ch h*128.
// 2 barriers/iter; DMA for kt+1 issued mid-iter (legal after barS) so the
// compiler's vmcnt(0)-before-barrier lands on a mostly-drained queue.
__global__ __launch_bounds__(256, 2) void k_attn(const char* __restrict__ Qg,
        const char* __restrict__ Kg, const char* __restrict__ Vg,
        bf16_t* __restrict__ Opb, float* __restrict__ Lp) {
    __shared__ __align__(16) char Ksh[2][16384];
    __shared__ __align__(16) char Vsh[2][16384];
    __shared__ __align__(16) char Psh[2][4096];
    int bid = blockIdx.x;               // 512 = b(2) x sp(4) x qt(64)
    int qt = bid & 63, sp = (bid >> 6) & 3, b = bid >> 8;
    int tid = threadIdx.x;
    int w = tid >> 6, lane = tid & 63, n15 = lane & 15, quad = lane >> 4;
    int r = w >> 1, h = w & 1;

    // Q fragments (SCL pre-folded): rows qt*64 + r*32 + g*16
    bf16x8 qf[2][8];
    const char* qb = Qg + (size_t)(b * 64 + qt) * 32768;
    #pragma unroll
    for (int g = 0; g < 2; ++g)
        #pragma unroll
        for (int ks = 0; ks < 8; ++ks)
            qf[g][ks] = *(const bf16x8*)(qb + (ks * 4 + r * 2 + g) * 1024 + lane * 16);

    bf16x8 onev;                        // ones B-fragment in registers
    #pragma unroll
    for (int j = 0; j < 8; ++j) onev[j] = (bf16_t)1.0f;

    f32x4 o[2][8] = {};                 // 32 rows x 128 ch
    f32x4 l2[2] = {};                   // row sums (ones-channel MFMA)

    int tbase = b * 128 + sp * 32;      // 32 tiles of 32 keys for this split
    {   // prologue: stage tile 0 -> buffer 0
        const char* kb = Kg + (size_t)tbase * 16384;
        const char* vb = Vg + (size_t)tbase * 16384;
        #pragma unroll
        for (int i = 0; i < 4; ++i) {
            int off = (w * 4 + i) * 1024 + lane * 16;
            gl16(kb + off, Ksh[0] + off);
            gl16(vb + off, Vsh[0] + off);
        }
    }
    for (int kt = 0; kt < 32; ++kt) {
        int p = kt & 1;
        __syncthreads();                              // barS: tile kt landed; prev bufs free
        // QK: 32 rows x 16 keys (half h)
        f32x4 s[2] = {};
        #pragma unroll
        for (int ks = 0; ks < 8; ++ks) {
            bf16x8 kf = *(const bf16x8*)(Ksh[p] + (ks * 2 + h) * 1024 + lane * 16);
            s[0] = MFMA16(qf[0][ks], kf, s[0]);
            s[1] = MFMA16(qf[1][ks], kf, s[1]);
        }
        // P = exp2(s)  (scale pre-folded, fixed-max), write A-frag image
        #pragma unroll
        for (int g = 0; g < 2; ++g)
            #pragma unroll
            for (int ri = 0; ri < 4; ++ri) {
                float pv = __builtin_amdgcn_exp2f(s[g][ri]);
                *(bf16_t*)(Psh[p] + (r * 2 + g) * 1024 +
                           (h * 2 + (n15 >> 3)) * 256 + (quad * 4 + ri) * 16 +
                           (n15 & 7) * 2) = (bf16_t)pv;
            }
        __syncthreads();                              // barP: P visible (vmcnt already 0 -> cheap)
        if (kt < 31) {                                // prefetch tile kt+1 into idle buffer
            const char* kb = Kg + (size_t)(tbase + kt + 1) * 16384;
            const char* vb = Vg + (size_t)(tbase + kt + 1) * 16384;
            #pragma unroll
            for (int i = 0; i < 4; ++i) {
                int off = (w * 4 + i) * 1024 + lane * 16;
                gl16(kb + off, Ksh[p ^ 1] + off);
                gl16(vb + off, Vsh[p ^ 1] + off);
            }
        }
        // PV: rows r*32 x ch-half h, all 32 keys; + ones-channel -> l
        bf16x8 pa0 = *(const bf16x8*)(Psh[p] + (r * 2 + 0) * 1024 + lane * 16);
        bf16x8 pa1 = *(const bf16x8*)(Psh[p] + (r * 2 + 1) * 1024 + lane * 16);
        l2[0] = MFMA16(pa0, onev, l2[0]);
        l2[1] = MFMA16(pa1, onev, l2[1]);
        #pragma unroll
        for (int ct = 0; ct < 8; ++ct) {
            bf16x8 vf = *(const bf16x8*)(Vsh[p] + (h * 8 + ct) * 1024 + lane * 16);
            o[0][ct] = MFMA16(pa0, vf, o[0][ct]);
            o[1][ct] = MFMA16(pa1, vf, o[1][ct]);
        }
    }
    // epilogue: unnormalized O (bf16) + l for this split
    int tok0 = b * N + qt * 64 + r * 32;
    #pragma unroll
    for (int g = 0; g < 2; ++g) {
        #pragma unroll
        for (int ct = 0; ct < 8; ++ct)
            #pragma unroll
            for (int ri = 0; ri < 4; ++ri)
                Opb[((size_t)sp * T + tok0 + g * 16 + quad * 4 + ri) * D +
                    h * 128 + ct * 16 + n15] = (bf16_t)o[g][ct][ri];
        if (h == 0 && n15 == 0) {
            #pragma unroll
            for (int ri = 0; ri < 4; ++ri)
                Lp[sp * T + tok0 + g * 16 + quad * 4 + ri] = l2[g][ri];
        }
    }
}

// ---- kernel 4: combine splits + normalize + recompute xn + residual --------
__global__ void k_comb(const bf16_t* __restrict__ Opb, const float* __restrict__ Lp,
                       const float4* __restrict__ part, const float* __restrict__ bn_w,
                       const float* __restrict__ bn_b, const float* __restrict__ x,
                       const float* __restrict__ gamma, float* __restrict__ out) {
    __shared__ float4 ssl[128];
    __shared__ float wts[32];
    __shared__ float Ot[256 * 33];
    int blk = blockIdx.x;                // 256 blocks x 32 tokens
    int b = blk >> 7, hw0 = (blk & 127) * 32;
    int tok0 = b * N + hw0;
    int tid = threadIdx.x;
    if (tid < 128) {
        float4 p0 = part[tid * 4 + 0], p1 = part[tid * 4 + 1];
        float4 p2 = part[tid * 4 + 2], p3 = part[tid * 4 + 3];
        float sr = p0.x + p1.x + p2.x + p3.x, si = p0.y + p1.y + p2.y + p3.y;
        float qr = p0.z + p1.z + p2.z + p3.z, qi = p0.w + p1.w + p2.w + p3.w;
        const float inv = 1.0f / (float)(Bn * N);
        float mr = sr * inv, mi = si * inv;
        float vr = qr * inv - mr * mr, vi = qi * inv - mi * mi;
        float scr = bn_w[tid * 2 + 0] * rsqrtf(vr + EPS);
        float sci = bn_w[tid * 2 + 1] * rsqrtf(vi + EPS);
        ssl[tid] = make_float4(scr, bn_b[tid * 2 + 0] - mr * scr,
                               sci, bn_b[tid * 2 + 1] - mi * sci);
    }
    if (tid < 32) {
        float Z = 0.f;
        #pragma unroll
        for (int s = 0; s < NSP; ++s) Z += Lp[s * T + tok0 + tid];
        wts[tid] = gamma[0] / Z;
    }
    __syncthreads();
    #pragma unroll
    for (int i = 0; i < 4; ++i) {
        int idx = i * 256 + tid;         // 1024 chunks of 8 ch
        int tk = idx >> 5, chunk = idx & 31;
        size_t base = (size_t)(tok0 + tk) * D + chunk * 8;
        float acc[8] = {};
        #pragma unroll
        for (int s = 0; s < NSP; ++s) {
            bf16x8 v = *(const bf16x8*)(Opb + (size_t)s * T * D + base);
            #pragma unroll
            for (int j = 0; j < 8; ++j) acc[j] += (float)v[j];
        }
        float ww = wts[tk];
        #pragma unroll
        for (int j = 0; j < 8; ++j) Ot[(chunk * 8 + j) * 33 + tk] = acc[j] * ww;
    }
    __syncthreads();
    const float2* xin = (const float2*)x;
    float2* xo = (float2*)out;
    #pragma unroll
    for (int i = 0; i < 16; ++i) {
        int linear = i * 256 + tid;
        int c = linear >> 5, hwo = linear & 31;
        size_t idx = (size_t)(b * Cc + c) * N + hw0 + hwo;
        float2 v = xin[idx];
        float4 s = ssl[c];
        float2 res;
        res.x = v.x * s.x + s.y + Ot[c * 33 + hwo];
        res.y = v.y * s.z + s.w + Ot[(128 + c) * 33 + hwo];
        xo[idx] = res;
    }
}

extern "C" void kernel_launch(void* const* d_in, const int* in_sizes, int n_in,
                              void* d_out, int out_size, void* d_ws, size_t ws_size,
                              hipStream_t stream) {
    const float* x    = (const float*)d_in[0];
    const float* bn_w = (const float*)d_in[1];
    const float* bn_b = (const float*)d_in[2];
    const float* wq   = (const float*)d_in[3];
    const float* bq   = (const float*)d_in[4];
    const float* wk   = (const float*)d_in[5];
    const float* bk   = (const float*)d_in[6];
    const float* wv   = (const float*)d_in[7];
    const float* bv   = (const float*)d_in[8];
    const float* gam  = (const float*)d_in[9];
    float* out = (float*)d_out;

    char* ws = (char*)d_ws;
    size_t off = 0;
    auto alloc = [&](size_t bytes) -> void* {
        void* p = ws + off;
        off += (bytes + 255) & ~(size_t)255;
        return p;
    };
    float4* part = (float4*)alloc(512 * sizeof(float4));
    char*   Wg   = (char*)alloc((size_t)12 * 32768);
    float*  bt   = (float*)alloc(768 * 4);
    char*   Qg   = (char*)alloc((size_t)128 * 32768);
    char*   Kg   = (char*)alloc((size_t)256 * 16384);
    char*   Vg   = (char*)alloc((size_t)256 * 16384);
    bf16_t* Opb  = (bf16_t*)alloc((size_t)NSP * T * D * 2);
    float*  Lp   = (float*)alloc((size_t)NSP * T * 4);

    k_pre<<<1280, 256, 0, stream>>>(x, part, wq, wk, wv, bq, bk, bv, Wg, bt);
    k_qkv<<<dim3(128, 12), 256, 0, stream>>>(x, part, bn_w, bn_b, Wg, bt, Qg, Kg, Vg);
    k_attn<<<512, 256, 0, stream>>>(Qg, Kg, Vg, Opb, Lp);
    k_comb<<<256, 256, 0, stream>>>(Opb, Lp, part, bn_w, bn_b, x, gam, out);
}